// Round 1
// baseline (1621.520 us; speedup 1.0000x reference)
//
#include <hip/hip_runtime.h>

typedef __bf16 bf16;
typedef __bf16 bf16x8 __attribute__((ext_vector_type(8)));
typedef __bf16 bf16x4 __attribute__((ext_vector_type(4)));
typedef float f32x4 __attribute__((ext_vector_type(4)));
typedef unsigned short u16x4 __attribute__((ext_vector_type(4)));
typedef __attribute__((address_space(3))) const void as3_void;

#define DEVI __device__ __forceinline__

// ---------------- conversion kernels ----------------
__global__ void k_cvt_bf16(const float* __restrict__ src, bf16* __restrict__ dst, int n4){
  int i = blockIdx.x*256 + threadIdx.x;
  if (i < n4){
    float4 v = reinterpret_cast<const float4*>(src)[i];
    bf16x4 o; o[0]=(bf16)v.x; o[1]=(bf16)v.y; o[2]=(bf16)v.z; o[3]=(bf16)v.w;
    reinterpret_cast<bf16x4*>(dst)[i] = o;
  }
}

// src: K x N (f32) -> dst: N x K (bf16)
__global__ void k_transpose_cvt(const float* __restrict__ src, bf16* __restrict__ dst, int K, int N){
  __shared__ float tile[32][33];
  int n0 = blockIdx.x*32, k0 = blockIdx.y*32;
  int tx = threadIdx.x & 31, ty = threadIdx.x >> 5; // 32 x 8
  #pragma unroll
  for (int i=0;i<32;i+=8)
    tile[ty+i][tx] = src[(size_t)(k0+ty+i)*N + n0+tx];
  __syncthreads();
  #pragma unroll
  for (int i=0;i<32;i+=8)
    dst[(size_t)(n0+ty+i)*K + k0+tx] = (bf16)tile[tx][ty+i];
}

// ---------------- 128x128 bf16 MFMA GEMM, A: MxK row-major, Bt: NxK row-major ----------------
// EPI==0: qkv epilogue (bias + split heads -> q/k/v [B,H,Q,128] bf16)
// EPI==1: proj epilogue (bias -> f32 out MxN)
template<int EPI>
__global__ __launch_bounds__(256,2) void k_gemm(
    const bf16* __restrict__ A, const bf16* __restrict__ Bt,
    const float* __restrict__ bias, int N, int K,
    bf16* __restrict__ q_out, bf16* __restrict__ k_out, bf16* __restrict__ v_out,
    float* __restrict__ c_out)
{
  __shared__ bf16 As[2][128*32];
  __shared__ bf16 Bs[2][128*32];
  const int t = threadIdx.x, w = t>>6, l = t&63;
  const int nb = N>>7;
  const int m0 = (blockIdx.x / nb)<<7, n0 = (blockIdx.x % nb)<<7;
  const bf16* Ab = A  + (size_t)m0*K;
  const bf16* Bb = Bt + (size_t)n0*K;
  f32x4 acc[4][4] = {};
  bf16x8 ra[2], rb[2];
  const int r0s = t>>2,        c0s = (t&3)*8;
  const int r1s = (t+256)>>2,  c1s = ((t+256)&3)*8;
  auto gload = [&](int k0){
    ra[0] = *reinterpret_cast<const bf16x8*>(Ab + (size_t)r0s*K + k0 + c0s);
    ra[1] = *reinterpret_cast<const bf16x8*>(Ab + (size_t)r1s*K + k0 + c1s);
    rb[0] = *reinterpret_cast<const bf16x8*>(Bb + (size_t)r0s*K + k0 + c0s);
    rb[1] = *reinterpret_cast<const bf16x8*>(Bb + (size_t)r1s*K + k0 + c1s);
  };
  gload(0);
  const int mw = (w&1)<<6, nw = (w>>1)<<6;
  const int nk = K>>5;
  for (int ks=0; ks<nk; ++ks){
    const int buf = ks&1;
    *reinterpret_cast<bf16x8*>(&As[buf][t*8])       = ra[0];
    *reinterpret_cast<bf16x8*>(&As[buf][(t+256)*8]) = ra[1];
    *reinterpret_cast<bf16x8*>(&Bs[buf][t*8])       = rb[0];
    *reinterpret_cast<bf16x8*>(&Bs[buf][(t+256)*8]) = rb[1];
    __syncthreads();
    if (ks+1 < nk) gload((ks+1)<<5);
    bf16x8 af[4], bfm[4];
    #pragma unroll
    for (int mf=0;mf<4;mf++)
      af[mf] = *reinterpret_cast<const bf16x8*>(&As[buf][(mw + mf*16 + (l&15))*32 + ((l>>4)<<3)]);
    #pragma unroll
    for (int nf=0;nf<4;nf++)
      bfm[nf] = *reinterpret_cast<const bf16x8*>(&Bs[buf][(nw + nf*16 + (l&15))*32 + ((l>>4)<<3)]);
    #pragma unroll
    for (int mf=0;mf<4;mf++)
      #pragma unroll
      for (int nf=0;nf<4;nf++)
        acc[mf][nf] = __builtin_amdgcn_mfma_f32_16x16x32_bf16(af[mf], bfm[nf], acc[mf][nf], 0,0,0);
    __syncthreads();
  }
  // epilogue: D layout (m89): col = lane&15, row = (lane>>4)*4 + reg
  if constexpr (EPI==0){
    #pragma unroll
    for (int nf=0;nf<4;nf++){
      const int col = n0 + nw + nf*16 + (l&15);
      const int sec = col>>11; const int rem = col&2047;
      const int hh = rem>>7;  const int dd = rem&127;
      bf16* dst = (sec==0) ? q_out : ((sec==1) ? k_out : v_out);
      const float bv = bias[col];
      #pragma unroll
      for (int mf=0;mf<4;mf++)
        #pragma unroll
        for (int ri=0;ri<4;ri++){
          const int row = m0 + mw + mf*16 + ((l>>4)<<2) + ri;
          const int bb = row>>10, qp = row&1023;
          dst[(((size_t)(bb*16+hh)*1024 + qp)<<7) + dd] = (bf16)(acc[mf][nf][ri] + bv);
        }
    }
  } else {
    #pragma unroll
    for (int nf=0;nf<4;nf++){
      const int col = n0 + nw + nf*16 + (l&15);
      const float bv = bias[col];
      #pragma unroll
      for (int mf=0;mf<4;mf++)
        #pragma unroll
        for (int ri=0;ri<4;ri++){
          const int row = m0 + mw + mf*16 + ((l>>4)<<2) + ri;
          c_out[(size_t)row*N + col] = acc[mf][nf][ri] + bv;
        }
    }
  }
}

// ---------------- fused paged + causal flash attention ----------------
// block = (b, h, 64-row q-tile); 4 waves x 16 q-rows; KV tiles of 64.
__global__ __launch_bounds__(256,2) void k_attn(
    const bf16* __restrict__ qb, const bf16* __restrict__ kb, const bf16* __restrict__ vb,
    const float* __restrict__ k_pages, const float* __restrict__ v_pages,
    const int* __restrict__ page_pos, const int* __restrict__ input_pos,
    bf16* __restrict__ ctx)
{
  __shared__ bf16 Ks[64*128];     // row-major [kv][d], XOR-swizzled
  __shared__ bf16 Vs[64*128];     // subtiled [p/4][d/16][4][16] for ds_read_b64_tr_b16
  __shared__ bf16 Ps[4][16*64];   // per-wave P, XOR-swizzled
  const int t = threadIdx.x, w = t>>6, l = t&63;
  const int blk = blockIdx.x;
  const int qt = blk & 15, h = (blk>>4)&15, b = blk>>8;
  const int q0 = (qt<<6) + (w<<4);
  const float scale = 0.088388347648318447f; // 1/sqrt(128)
  const size_t bh = (size_t)(b*16 + h);

  // Q fragments in registers: A[row][k]: row = l&15, k = (l>>4)*8+e
  const bf16* qptr = qb + (bh<<17);
  bf16x8 qf[4];
  {
    const int qrow = q0 + (l&15);
    #pragma unroll
    for (int kc=0;kc<4;kc++)
      qf[kc] = *reinterpret_cast<const bf16x8*>(qptr + ((size_t)qrow<<7) + kc*32 + ((l>>4)<<3));
  }
  f32x4 o[8] = {};
  float mrow[4] = {-1e30f,-1e30f,-1e30f,-1e30f};
  float lsum[4] = {0.f,0.f,0.f,0.f};
  bf16* Pw = &Ps[w][0];

  auto stage_f32 = [&](const float* __restrict__ ks_src, const float* __restrict__ vs_src){
    #pragma unroll
    for (int j=0;j<8;j++){
      const int f = t + (j<<8);
      { // K: row-major + XOR swizzle
        const int r = f>>5, c = (f&31)<<2;
        float4 kv = *reinterpret_cast<const float4*>(ks_src + ((size_t)r<<7) + c);
        unsigned a = (unsigned)((r<<8) + (c<<1)); a ^= (unsigned)((r&7)<<4);
        bf16x4 t4; t4[0]=(bf16)kv.x; t4[1]=(bf16)kv.y; t4[2]=(bf16)kv.z; t4[3]=(bf16)kv.w;
        *reinterpret_cast<bf16x4*>(reinterpret_cast<char*>(Ks) + a) = t4;
      }
      { // V: subtiled, linear LDS writes (conflict-free)
        const int u = f;
        const int p = ((u>>7)<<2) + ((u>>2)&3);
        const int d = (((u>>4)&7)<<4) + ((u&3)<<2);
        float4 vv = *reinterpret_cast<const float4*>(vs_src + ((size_t)p<<7) + d);
        bf16x4 t4; t4[0]=(bf16)vv.x; t4[1]=(bf16)vv.y; t4[2]=(bf16)vv.z; t4[3]=(bf16)vv.w;
        *reinterpret_cast<bf16x4*>(reinterpret_cast<char*>(Vs) + u*8) = t4;
      }
    }
  };
  auto stage_bf16 = [&](const bf16* __restrict__ ks_src, const bf16* __restrict__ vs_src){
    #pragma unroll
    for (int j=0;j<8;j++){
      const int f = t + (j<<8);
      {
        const int r = f>>5, c = (f&31)<<2;
        bf16x4 kv = *reinterpret_cast<const bf16x4*>(ks_src + ((size_t)r<<7) + c);
        unsigned a = (unsigned)((r<<8) + (c<<1)); a ^= (unsigned)((r&7)<<4);
        *reinterpret_cast<bf16x4*>(reinterpret_cast<char*>(Ks) + a) = kv;
      }
      {
        const int u = f;
        const int p = ((u>>7)<<2) + ((u>>2)&3);
        const int d = (((u>>4)&7)<<4) + ((u&3)<<2);
        bf16x4 vv = *reinterpret_cast<const bf16x4*>(vs_src + ((size_t)p<<7) + d);
        *reinterpret_cast<bf16x4*>(reinterpret_cast<char*>(Vs) + u*8) = vv;
      }
    }
  };

  auto process = [&](int lo, int hi, bool causal, int ktg){
    // S = Q K^T  (B[k=d][col=kv]: lane reads K[cb*16+(l&15)][kc*32+(l>>4)*8 ..+7])
    f32x4 s[4];
    #pragma unroll
    for (int cb=0;cb<4;cb++){
      f32x4 a_ = {};
      #pragma unroll
      for (int kc=0;kc<4;kc++){
        const int krow = (cb<<4) + (l&15);
        unsigned a = (unsigned)((krow<<8) + (kc<<6) + ((l>>4)<<4)); a ^= (unsigned)((krow&7)<<4);
        bf16x8 kf = *reinterpret_cast<const bf16x8*>(reinterpret_cast<const char*>(Ks) + a);
        a_ = __builtin_amdgcn_mfma_f32_16x16x32_bf16(qf[kc], kf, a_, 0,0,0);
      }
      s[cb] = a_;
    }
    // scale + mask (D rows = (l>>4)*4+ri, cols = cb*16+(l&15))
    #pragma unroll
    for (int cb=0;cb<4;cb++){
      const int col = (cb<<4) + (l&15);
      const bool v0 = (col >= lo) && (col < hi);
      #pragma unroll
      for (int ri=0;ri<4;ri++){
        bool ok = v0;
        if (causal) ok = ok && ((ktg + col) <= (q0 + ((l>>4)<<2) + ri));
        s[cb][ri] = ok ? s[cb][ri]*scale : -1e30f;
      }
    }
    // online softmax: row reductions across the 16 lanes of each (l>>4) group
    float tm[4];
    #pragma unroll
    for (int ri=0;ri<4;ri++)
      tm[ri] = fmaxf(fmaxf(s[0][ri],s[1][ri]), fmaxf(s[2][ri],s[3][ri]));
    #pragma unroll
    for (int d_=1; d_<16; d_<<=1)
      #pragma unroll
      for (int ri=0;ri<4;ri++)
        tm[ri] = fmaxf(tm[ri], __shfl_xor(tm[ri], d_, 64));
    float al[4];
    #pragma unroll
    for (int ri=0;ri<4;ri++){
      const float mn = fmaxf(mrow[ri], tm[ri]);
      al[ri] = __expf(mrow[ri] - mn);
      mrow[ri] = mn;
    }
    f32x4 p[4];
    #pragma unroll
    for (int cb=0;cb<4;cb++)
      #pragma unroll
      for (int ri=0;ri<4;ri++)
        p[cb][ri] = __expf(s[cb][ri] - mrow[ri]);
    #pragma unroll
    for (int ri=0;ri<4;ri++){
      float sm = p[0][ri]+p[1][ri]+p[2][ri]+p[3][ri];
      #pragma unroll
      for (int d_=1; d_<16; d_<<=1) sm += __shfl_xor(sm, d_, 64);
      lsum[ri] = lsum[ri]*al[ri] + sm;
    }
    #pragma unroll
    for (int dcb=0;dcb<8;dcb++)
      #pragma unroll
      for (int ri=0;ri<4;ri++)
        o[dcb][ri] *= al[ri];
    // P -> per-wave LDS (swizzled), reload as A-fragments
    #pragma unroll
    for (int cb=0;cb<4;cb++)
      #pragma unroll
      for (int ri=0;ri<4;ri++){
        const int row = ((l>>4)<<2) + ri;
        const int col = (cb<<4) + (l&15);
        unsigned a = (unsigned)((row<<7) + (col<<1)); a ^= (unsigned)((row&7)<<4);
        *reinterpret_cast<bf16*>(reinterpret_cast<char*>(Pw) + a) = (bf16)p[cb][ri];
      }
    bf16x8 pa[2];
    #pragma unroll
    for (int pc=0;pc<2;pc++){
      const int row = l&15;
      unsigned a = (unsigned)((row<<7) + (pc<<6) + ((l>>4)<<4)); a ^= (unsigned)((row&7)<<4);
      pa[pc] = *reinterpret_cast<const bf16x8*>(reinterpret_cast<const char*>(Pw) + a);
    }
    // PV: B-frags via hardware transpose read from subtiled Vs
    #pragma unroll
    for (int pc=0;pc<2;pc++)
      #pragma unroll
      for (int dcb=0;dcb<8;dcb++){
        const unsigned sub = ((unsigned)((pc*8 + ((l>>4)<<1))*8 + dcb)<<7) + ((l&15)<<3);
        u16x4 r0, r1;
        as3_void* pl = (as3_void*)(reinterpret_cast<const char*>(Vs) + sub);
        asm volatile("ds_read_b64_tr_b16 %0, %2 offset:0\n\t"
                     "ds_read_b64_tr_b16 %1, %2 offset:1024\n\t"
                     "s_waitcnt lgkmcnt(0)"
                     : "=&v"(r0), "=&v"(r1) : "v"(pl) : "memory");
        union { unsigned short us[8]; bf16x8 v; } uu;
        #pragma unroll
        for (int i=0;i<4;i++){ uu.us[i]=r0[i]; uu.us[4+i]=r1[i]; }
        o[dcb] = __builtin_amdgcn_mfma_f32_16x16x32_bf16(pa[pc], uu.v, o[dcb], 0,0,0);
      }
  };

  // ---- paged KV ----
  for (int pg=0; pg<8; ++pg){
    const size_t pbase = ((((size_t)pg*8 + b)*16) + h) << 15; // *256*128
    const float* kp = k_pages + pbase;
    const float* vp = v_pages + pbase;
    const int start = page_pos[(pg*8+b)*2 + 0];
    const int plen  = page_pos[(pg*8+b)*2 + 1];
    for (int to=0; to<4; ++to){
      __syncthreads();
      stage_f32(kp + to*64*128, vp + to*64*128);
      __syncthreads();
      process(start - to*64, start + plen - to*64, false, 0);
    }
  }
  // ---- current chunk (causal) ----
  {
    const bf16* kcb = kb + (bh<<17);
    const bf16* vcb = vb + (bh<<17);
    const int len_b = input_pos[b*2+1];
    for (int kt=0; kt<=qt; ++kt){
      __syncthreads();
      stage_bf16(kcb + ((size_t)kt<<13), vcb + ((size_t)kt<<13));
      __syncthreads();
      int hi = len_b - (kt<<6); hi = hi < 64 ? hi : 64;
      process(0, hi, kt==qt, kt<<6);
    }
  }
  // ---- epilogue: ctx[b][qp][h*128 + d] (bf16) ----
  #pragma unroll
  for (int ri=0;ri<4;ri++){
    const float inv = 1.f / fmaxf(lsum[ri], 1e-9f);
    const int qp = q0 + ((l>>4)<<2) + ri;
    #pragma unroll
    for (int dcb=0;dcb<8;dcb++)
      ctx[((size_t)(b*1024 + qp)<<11) + (h<<7) + (dcb<<4) + (l&15)] = (bf16)(o[dcb][ri]*inv);
  }
}

// ---------------- launcher ----------------
extern "C" void kernel_launch(void* const* d_in, const int* in_sizes, int n_in,
                              void* d_out, int out_size, void* d_ws, size_t ws_size,
                              hipStream_t stream)
{
  const float* hidden  = (const float*)d_in[0];
  const float* W_attn  = (const float*)d_in[1];
  const float* b_attn  = (const float*)d_in[2];
  const float* W_proj  = (const float*)d_in[3];
  const float* b_proj  = (const float*)d_in[4];
  const float* k_pages = (const float*)d_in[5];
  const float* v_pages = (const float*)d_in[6];
  const int*   page_pos  = (const int*)d_in[7];
  const int*   input_pos = (const int*)d_in[8];
  float* out = (float*)d_out;
  char* ws = (char*)d_ws;
  bf16* A1  = (bf16*)(ws);              // 8192x2048 bf16 (32MB); reused as ctx
  bf16* Wt1 = (bf16*)(ws + 33554432);   // 6144x2048 bf16 (24MB)
  bf16* Wt2 = (bf16*)(ws + 58720256);   // 2048x2048 bf16 (8MB)
  bf16* qb  = (bf16*)(ws + 67108864);   // [8,16,1024,128] bf16 (32MB)
  bf16* kb  = (bf16*)(ws + 100663296);
  bf16* vb  = (bf16*)(ws + 134217728);  // end: 167,772,160 bytes
  bf16* ctx = A1;

  k_cvt_bf16<<<16384, 256, 0, stream>>>(hidden, A1, 8192*2048/4);
  k_transpose_cvt<<<dim3(192,64), 256, 0, stream>>>(W_attn, Wt1, 2048, 6144);
  k_transpose_cvt<<<dim3(64,64),  256, 0, stream>>>(W_proj, Wt2, 2048, 2048);
  k_gemm<0><<<64*48, 256, 0, stream>>>(A1, Wt1, b_attn, 6144, 2048, qb, kb, vb, nullptr);
  k_attn<<<2048, 256, 0, stream>>>(qb, kb, vb, k_pages, v_pages, page_pos, input_pos, ctx);
  k_gemm<1><<<64*16, 256, 0, stream>>>(ctx, Wt2, b_proj, 2048, 2048, nullptr, nullptr, nullptr, out);
}

// Round 2
// 826.983 us; speedup vs baseline: 1.9608x; 1.9608x over previous
//
#include <hip/hip_runtime.h>

typedef __bf16 bf16;
typedef __bf16 bf16x8 __attribute__((ext_vector_type(8)));
typedef __bf16 bf16x4 __attribute__((ext_vector_type(4)));
typedef float f32x4 __attribute__((ext_vector_type(4)));
typedef unsigned short u16x4 __attribute__((ext_vector_type(4)));
typedef __attribute__((address_space(3))) const void as3_void;

#define GLOAD16(G,L) __builtin_amdgcn_global_load_lds((__attribute__((address_space(1))) const void*)(G), (__attribute__((address_space(3))) void*)(L), 16, 0, 0)

// ---------------- conversion kernels ----------------
__global__ void k_cvt_bf16(const float* __restrict__ src, bf16* __restrict__ dst, int n4){
  int i = blockIdx.x*256 + threadIdx.x;
  if (i < n4){
    float4 v = reinterpret_cast<const float4*>(src)[i];
    bf16x4 o; o[0]=(bf16)v.x; o[1]=(bf16)v.y; o[2]=(bf16)v.z; o[3]=(bf16)v.w;
    reinterpret_cast<bf16x4*>(dst)[i] = o;
  }
}

// src: K x N (f32) -> dst: N x K (bf16)
__global__ void k_transpose_cvt(const float* __restrict__ src, bf16* __restrict__ dst, int K, int N){
  __shared__ float tile[32][33];
  int n0 = blockIdx.x*32, k0 = blockIdx.y*32;
  int tx = threadIdx.x & 31, ty = threadIdx.x >> 5; // 32 x 8
  #pragma unroll
  for (int i=0;i<32;i+=8)
    tile[ty+i][tx] = src[(size_t)(k0+ty+i)*N + n0+tx];
  __syncthreads();
  #pragma unroll
  for (int i=0;i<32;i+=8)
    dst[(size_t)(n0+ty+i)*K + k0+tx] = (bf16)tile[tx][ty+i];
}

// ---------------- 128x128 bf16 MFMA GEMM (m97 structure: global_load_lds + dbuf) ----------------
// A: MxK row-major, Bt: NxK row-major
// EPI==0: qkv epilogue (bias + split heads -> q/k/v [B,H,Q,128] bf16)
// EPI==1: proj epilogue (bias -> f32 out MxN)
template<int EPI>
__global__ __launch_bounds__(256,2) void k_gemm(
    const bf16* __restrict__ A, const bf16* __restrict__ Bt,
    const float* __restrict__ bias, int N, int K,
    bf16* __restrict__ q_out, bf16* __restrict__ k_out, bf16* __restrict__ v_out,
    float* __restrict__ c_out)
{
  __shared__ bf16 As[2][128*32];
  __shared__ bf16 Bs[2][128*32];
  const int t = threadIdx.x, w = t>>6, l = t&63, g = l>>4;
  const int nb = N>>7;
  const int m0 = (blockIdx.x / nb)<<7, n0 = (blockIdx.x % nb)<<7;
  const bf16* Ab = A  + (size_t)m0*K;
  const bf16* Bb = Bt + (size_t)n0*K;
  // per-thread source offsets (elements): slot = t + j*256, r = slot>>2, c = (slot&3)*8
  size_t sOff[2];
  #pragma unroll
  for (int j=0;j<2;j++){
    int slot = t + (j<<8);
    sOff[j] = (size_t)(slot>>2)*K + ((slot&3)<<3);
  }
  auto stage = [&](int k0, int buf){
    char* ad = (char*)As + (buf<<13) + (w<<10);
    char* bd = (char*)Bs + (buf<<13) + (w<<10);
    #pragma unroll
    for (int j=0;j<2;j++){
      GLOAD16(Ab + sOff[j] + k0, ad + (j<<12));
      GLOAD16(Bb + sOff[j] + k0, bd + (j<<12));
    }
  };
  f32x4 acc[4][4] = {};
  const int mw = (w&1)<<6, nw = (w>>1)<<6;
  const int nk = K>>5;
  int buf = 0;
  stage(0, 0);
  asm volatile("s_waitcnt vmcnt(0)" ::: "memory");
  __syncthreads();
  for (int ks=0; ks<nk; ++ks){
    if (ks+1 < nk) stage((ks+1)<<5, buf^1);
    bf16x8 af[4], bfm[4];
    #pragma unroll
    for (int mf=0;mf<4;mf++)
      af[mf] = *reinterpret_cast<const bf16x8*>(&As[buf][(mw + mf*16 + (l&15))*32 + (g<<3)]);
    #pragma unroll
    for (int nf=0;nf<4;nf++)
      bfm[nf] = *reinterpret_cast<const bf16x8*>(&Bs[buf][(nw + nf*16 + (l&15))*32 + (g<<3)]);
    #pragma unroll
    for (int mf=0;mf<4;mf++)
      #pragma unroll
      for (int nf=0;nf<4;nf++)
        acc[mf][nf] = __builtin_amdgcn_mfma_f32_16x16x32_bf16(af[mf], bfm[nf], acc[mf][nf], 0,0,0);
    asm volatile("s_waitcnt vmcnt(0)" ::: "memory");
    __syncthreads();
    buf ^= 1;
  }
  // epilogue: D layout: col = lane&15, row = (lane>>4)*4 + reg
  if constexpr (EPI==0){
    #pragma unroll
    for (int nf=0;nf<4;nf++){
      const int col = n0 + nw + nf*16 + (l&15);
      const int sec = col>>11; const int rem = col&2047;
      const int hh = rem>>7;  const int dd = rem&127;
      bf16* dst = (sec==0) ? q_out : ((sec==1) ? k_out : v_out);
      const float bv = bias[col];
      #pragma unroll
      for (int mf=0;mf<4;mf++)
        #pragma unroll
        for (int ri=0;ri<4;ri++){
          const int row = m0 + mw + mf*16 + (g<<2) + ri;
          const int bb = row>>10, qp = row&1023;
          dst[(((size_t)(bb*16+hh)*1024 + qp)<<7) + dd] = (bf16)(acc[mf][nf][ri] + bv);
        }
    }
  } else {
    #pragma unroll
    for (int nf=0;nf<4;nf++){
      const int col = n0 + nw + nf*16 + (l&15);
      const float bv = bias[col];
      #pragma unroll
      for (int mf=0;mf<4;mf++)
        #pragma unroll
        for (int ri=0;ri<4;ri++){
          const int row = m0 + mw + mf*16 + (g<<2) + ri;
          c_out[(size_t)row*N + col] = acc[mf][nf][ri] + bv;
        }
    }
  }
}

// ---------------- fused paged + causal flash attention ----------------
// block = (b, h, 128-row q-tile); 4 waves x 32 q-rows (mq=2 x 16).
// Swapped QK^T: S^T = mfma(K, Q) -> lane holds q = l&15, kv = cb*16 + 4g + ri.
// V rows pi-permuted in LDS so PV A-frag = pure register repack (no shuffles, no P-LDS).
__global__ __launch_bounds__(256,2) void k_attn(
    const bf16* __restrict__ qb, const bf16* __restrict__ kb, const bf16* __restrict__ vb,
    const bf16* __restrict__ kpb, const bf16* __restrict__ vpb,
    const int* __restrict__ page_pos, const int* __restrict__ input_pos,
    bf16* __restrict__ ctx)
{
  __shared__ bf16 Ks[2*64*128];   // [buf][kv][d] row-major, XOR-swizzled (swz on read, inv-swz source)
  __shared__ bf16 Vs[2*64*128];   // [buf] subtiled for ds_read_b64_tr_b16, rows pi-permuted
  const int t = threadIdx.x, w = t>>6, l = t&63, g = l>>4, c = l&15;
  // XCD-aware bijective swizzle (nwg=1024, 1024%8==0): all 8 q-tiles of one (b,h) on one XCD
  const int bid = blockIdx.x;
  const int wg = (bid&7)*128 + (bid>>3);
  const int qt = wg & 7, h = (wg>>3)&15, b = wg>>7;
  const int q0w = (qt<<7) + (w<<5);
  const float scale = 0.088388347648318447f; // 1/sqrt(128)
  const size_t bh = (size_t)(b*16 + h);

  // Q as B-frags: B[k=d][col=q]: lane holds q = q0w + mq*16 + c, d = kc*32 + g*8 + e
  const bf16* qptr = qb + (bh<<17);
  bf16x8 qf[2][4];
  #pragma unroll
  for (int mq=0;mq<2;mq++)
    #pragma unroll
    for (int kc=0;kc<4;kc++)
      qf[mq][kc] = *reinterpret_cast<const bf16x8*>(qptr + ((size_t)(q0w + mq*16 + c)<<7) + kc*32 + (g<<3));

  // per-lane constant staging source offsets (elements)
  int kOff[4], vOff[4];
  #pragma unroll
  for (int j=0;j<4;j++){
    const int slot = t + (j<<8);
    { // K: linear LDS dest; source inverse-swizzled so swizzled reads see row-major
      const int a = slot<<4; const int r = a>>8; const int co = (a&255) ^ ((r&7)<<4);
      kOff[j] = (r<<7) + (co>>1);
    }
    { // V: subtiled dest slot s covers u={2s,2s+1}: p = same, d0..d0+7 contiguous
      const int s_ = slot;
      const int p  = ((s_>>6)<<2) | ((s_>>1)&3);
      const int d0 = (((s_>>3)&7)<<4) | ((s_&1)<<3);
      const int pp = (p&32) | ((p&4)<<2) | (((p>>3)&3)<<2) | (p&3); // pi(p)
      vOff[j] = (pp<<7) + d0;
    }
  }
  const bf16* kcb = kb + (bh<<17);
  const bf16* vcb = vb + (bh<<17);
  const int len_b = input_pos[b*2+1];
  const int NT = 32 + ((qt+1)<<1);

  f32x4 o[2][8] = {};
  float mrow[2] = {-3e38f,-3e38f};
  float lsum[2] = {0.f,0.f};

  auto tsrc = [&](int T, const bf16*& ks, const bf16*& vs_){
    if (T < 32){
      size_t pb = ((((size_t)(T>>2)<<3) + (size_t)b)*16 + (size_t)h) << 15;
      size_t off = (size_t)(T&3)<<13;
      ks = kpb + pb + off; vs_ = vpb + pb + off;
    } else {
      int kt = T-32; ks = kcb + ((size_t)kt<<13); vs_ = vcb + ((size_t)kt<<13);
    }
  };
  auto stage = [&](int T, int buf){
    const bf16 *ks, *vs_; tsrc(T, ks, vs_);
    char* kd = (char*)Ks + (buf<<14) + (w<<10);
    char* vd = (char*)Vs + (buf<<14) + (w<<10);
    #pragma unroll
    for (int j=0;j<4;j++){
      GLOAD16(ks  + kOff[j], kd + (j<<12));
      GLOAD16(vs_ + vOff[j], vd + (j<<12));
    }
  };

  auto process = [&](int buf, int lo, int hi, bool causal, int ktg){
    const char* Kb = (const char*)Ks + (buf<<14);
    const char* Vb = (const char*)Vs + (buf<<14);
    // QK^T (swapped): s[cb][mq], lane: q = q0w+mq*16+c, kv = cb*16 + 4g + ri
    f32x4 s[4][2] = {{},{},{},{}};
    #pragma unroll
    for (int kc=0;kc<4;kc++){
      bf16x8 kf[4];
      #pragma unroll
      for (int cb=0;cb<4;cb++){
        const int krow = (cb<<4) + c;
        unsigned a = (unsigned)((krow<<8) + (kc<<6) + (g<<4)); a ^= (unsigned)((krow&7)<<4);
        kf[cb] = *reinterpret_cast<const bf16x8*>(Kb + a);
      }
      #pragma unroll
      for (int cb=0;cb<4;cb++)
        #pragma unroll
        for (int mq=0;mq<2;mq++)
          s[cb][mq] = __builtin_amdgcn_mfma_f32_16x16x32_bf16(kf[cb], qf[mq][kc], s[cb][mq], 0,0,0);
    }
    // mask + scale
    #pragma unroll
    for (int cb=0;cb<4;cb++)
      #pragma unroll
      for (int ri=0;ri<4;ri++){
        const int kvl = (cb<<4) + (g<<2) + ri;
        const bool vok = (kvl >= lo) && (kvl < hi);
        #pragma unroll
        for (int mq=0;mq<2;mq++){
          bool ok = vok;
          if (causal) ok = ok && ((ktg + kvl) <= (q0w + mq*16 + c));
          s[cb][mq][ri] = ok ? s[cb][mq][ri]*scale : -3e38f;
        }
      }
    // online softmax (per mq; row = lane's c, slices spread over g)
    #pragma unroll
    for (int mq=0;mq<2;mq++){
      float mx = s[0][mq][0];
      #pragma unroll
      for (int cb=0;cb<4;cb++)
        #pragma unroll
        for (int ri=0;ri<4;ri++) mx = fmaxf(mx, s[cb][mq][ri]);
      mx = fmaxf(mx, __shfl_xor(mx, 16, 64));
      mx = fmaxf(mx, __shfl_xor(mx, 32, 64));
      const float mn = fmaxf(mrow[mq], mx);
      const float al = __expf(mrow[mq] - mn);
      mrow[mq] = mn;
      float ps = 0.f;
      #pragma unroll
      for (int cb=0;cb<4;cb++)
        #pragma unroll
        for (int ri=0;ri<4;ri++){
          const float e = __expf(s[cb][mq][ri] - mn);
          s[cb][mq][ri] = e; ps += e;
        }
      lsum[mq] = lsum[mq]*al + ps;
      #pragma unroll
      for (int ri=0;ri<4;ri++){
        const float av = __shfl(al, (l&48) | ((g<<2)+ri), 64);
        #pragma unroll
        for (int dcb=0;dcb<8;dcb++) o[mq][dcb][ri] *= av;
      }
    }
    // PV: A-frag from registers (pi-matched), B-frag via tr_read; V-frag shared across mq
    #pragma unroll
    for (int kc=0;kc<2;kc++){
      bf16x8 pav[2];
      #pragma unroll
      for (int mq=0;mq<2;mq++)
        #pragma unroll
        for (int e=0;e<8;e++)
          pav[mq][e] = (bf16)s[(kc<<1)+(e>>2)][mq][e&3];
      #pragma unroll
      for (int dcb=0;dcb<8;dcb++){
        const unsigned sub = ((unsigned)((((kc<<3) + (g<<1))<<3) + dcb)<<7) + ((unsigned)c<<3);
        u16x4 r0, r1;
        as3_void* pl = (as3_void*)(Vb + sub);
        asm volatile("ds_read_b64_tr_b16 %0, %2 offset:0\n\t"
                     "ds_read_b64_tr_b16 %1, %2 offset:1024\n\t"
                     "s_waitcnt lgkmcnt(0)"
                     : "=&v"(r0), "=&v"(r1) : "v"(pl) : "memory");
        union { unsigned short us[8]; bf16x8 v; } uu;
        #pragma unroll
        for (int i=0;i<4;i++){ uu.us[i]=r0[i]; uu.us[4+i]=r1[i]; }
        #pragma unroll
        for (int mq=0;mq<2;mq++)
          o[mq][dcb] = __builtin_amdgcn_mfma_f32_16x16x32_bf16(pav[mq], uu.v, o[mq][dcb], 0,0,0);
      }
    }
  };

  // ---- pipelined tile loop: stage(T+1) || process(T) ----
  int buf = 0;
  stage(0, 0);
  asm volatile("s_waitcnt vmcnt(0)" ::: "memory");
  __syncthreads();
  for (int T=0; T<NT; ++T){
    if (T+1 < NT) stage(T+1, buf^1);
    int lo, hi, ktg; bool causal;
    if (T < 32){
      const int pg = T>>2, to = T&3;
      const int start = page_pos[(pg*8+b)*2], plen = page_pos[(pg*8+b)*2+1];
      lo = start - (to<<6); hi = start + plen - (to<<6); causal = false; ktg = 0;
    } else {
      const int kt = T-32; lo = 0; hi = len_b - (kt<<6); if (hi>64) hi=64; causal = true; ktg = kt<<6;
    }
    process(buf, lo, hi, causal, ktg);
    asm volatile("s_waitcnt vmcnt(0)" ::: "memory");
    __syncthreads();
    buf ^= 1;
  }

  // ---- epilogue: ctx[b][q][h*128+d] (bf16); q = q0w + mq*16 + 4g + ri, d = dcb*16 + c ----
  #pragma unroll
  for (int mq=0;mq<2;mq++){
    float tl = lsum[mq];
    tl += __shfl_xor(tl, 16, 64);
    tl += __shfl_xor(tl, 32, 64);
    const float inv = 1.f / fmaxf(tl, 1e-9f);
    #pragma unroll
    for (int ri=0;ri<4;ri++){
      const float iv = __shfl(inv, (l&48) | ((g<<2)+ri), 64);
      const int q = q0w + mq*16 + (g<<2) + ri;
      #pragma unroll
      for (int dcb=0;dcb<8;dcb++)
        ctx[(((size_t)(b<<10) + q)<<11) + (h<<7) + (dcb<<4) + c] = (bf16)(o[mq][dcb][ri]*iv);
    }
  }
}

// ---------------- launcher ----------------
extern "C" void kernel_launch(void* const* d_in, const int* in_sizes, int n_in,
                              void* d_out, int out_size, void* d_ws, size_t ws_size,
                              hipStream_t stream)
{
  const float* hidden  = (const float*)d_in[0];
  const float* W_attn  = (const float*)d_in[1];
  const float* b_attn  = (const float*)d_in[2];
  const float* W_proj  = (const float*)d_in[3];
  const float* b_proj  = (const float*)d_in[4];
  const float* k_pages = (const float*)d_in[5];
  const float* v_pages = (const float*)d_in[6];
  const int*   page_pos  = (const int*)d_in[7];
  const int*   input_pos = (const int*)d_in[8];
  float* out = (float*)d_out;
  char* ws = (char*)d_ws;
  bf16* A1  = (bf16*)(ws);              // 8192x2048 bf16 (32MB); reused as ctx
  bf16* Wt1 = (bf16*)(ws + 33554432);   // 6144x2048 bf16 (24MB)
  bf16* Wt2 = (bf16*)(ws + 58720256);   // 2048x2048 bf16 (8MB)
  bf16* qb  = (bf16*)(ws + 67108864);   // [8,16,1024,128] bf16 (32MB)
  bf16* kb  = (bf16*)(ws + 100663296);
  bf16* vb  = (bf16*)(ws + 134217728);
  bf16* kpb = (bf16*)(ws + 167772160);  // bf16 pages (64MB)
  bf16* vpb = (bf16*)(ws + 234881024);  // bf16 pages (64MB); end 301,989,888
  bf16* ctx = A1;

  k_cvt_bf16<<<16384, 256, 0, stream>>>(hidden, A1, 4194304);
  k_cvt_bf16<<<32768, 256, 0, stream>>>(k_pages, kpb, 8388608);
  k_cvt_bf16<<<32768, 256, 0, stream>>>(v_pages, vpb, 8388608);
  k_transpose_cvt<<<dim3(192,64), 256, 0, stream>>>(W_attn, Wt1, 2048, 6144);
  k_transpose_cvt<<<dim3(64,64),  256, 0, stream>>>(W_proj, Wt2, 2048, 2048);
  k_gemm<0><<<64*48, 256, 0, stream>>>(A1, Wt1, b_attn, 6144, 2048, qb, kb, vb, nullptr);
  k_attn<<<1024, 256, 0, stream>>>(qb, kb, vb, kpb, vpb, page_pos, input_pos, ctx);
  k_gemm<1><<<64*16, 256, 0, stream>>>(ctx, Wt2, b_proj, 2048, 2048, nullptr, nullptr, nullptr, out);
}

// Round 3
// 801.989 us; speedup vs baseline: 2.0219x; 1.0312x over previous
//
#include <hip/hip_runtime.h>

typedef __bf16 bf16;
typedef __bf16 bf16x8 __attribute__((ext_vector_type(8)));
typedef __bf16 bf16x4 __attribute__((ext_vector_type(4)));
typedef float f32x4 __attribute__((ext_vector_type(4)));
typedef unsigned short u16x4 __attribute__((ext_vector_type(4)));
typedef __attribute__((address_space(3))) const void as3_void;

#define GLOAD16(G,L) __builtin_amdgcn_global_load_lds((__attribute__((address_space(1))) const void*)(G), (__attribute__((address_space(3))) void*)(L), 16, 0, 0)

// ---------------- conversion kernels ----------------
__global__ void k_cvt_bf16(const float* __restrict__ src, bf16* __restrict__ dst, int n4){
  int i = blockIdx.x*256 + threadIdx.x;
  if (i < n4){
    float4 v = reinterpret_cast<const float4*>(src)[i];
    bf16x4 o; o[0]=(bf16)v.x; o[1]=(bf16)v.y; o[2]=(bf16)v.z; o[3]=(bf16)v.w;
    reinterpret_cast<bf16x4*>(dst)[i] = o;
  }
}

// src: K x N (f32) -> dst: N x K (bf16)
__global__ void k_transpose_cvt(const float* __restrict__ src, bf16* __restrict__ dst, int K, int N){
  __shared__ float tile[32][33];
  int n0 = blockIdx.x*32, k0 = blockIdx.y*32;
  int tx = threadIdx.x & 31, ty = threadIdx.x >> 5; // 32 x 8
  #pragma unroll
  for (int i=0;i<32;i+=8)
    tile[ty+i][tx] = src[(size_t)(k0+ty+i)*N + n0+tx];
  __syncthreads();
  #pragma unroll
  for (int i=0;i<32;i+=8)
    dst[(size_t)(n0+ty+i)*K + k0+tx] = (bf16)tile[tx][ty+i];
}

// ---------------- 128x128 bf16 MFMA GEMM (m97 structure: global_load_lds + dbuf) ----------------
// A: MxK row-major, Bt: NxK row-major
// EPI==0: qkv epilogue (bias + split heads -> q/k/v [B,H,Q,128] bf16)
// EPI==1: proj epilogue (bias -> f32 out MxN)
template<int EPI>
__global__ __launch_bounds__(256,2) void k_gemm(
    const bf16* __restrict__ A, const bf16* __restrict__ Bt,
    const float* __restrict__ bias, int N, int K,
    bf16* __restrict__ q_out, bf16* __restrict__ k_out, bf16* __restrict__ v_out,
    float* __restrict__ c_out)
{
  __shared__ bf16 As[2][128*32];
  __shared__ bf16 Bs[2][128*32];
  const int t = threadIdx.x, w = t>>6, l = t&63, g = l>>4;
  const int nb = N>>7;
  const int m0 = (blockIdx.x / nb)<<7, n0 = (blockIdx.x % nb)<<7;
  const bf16* Ab = A  + (size_t)m0*K;
  const bf16* Bb = Bt + (size_t)n0*K;
  size_t sOff[2];
  #pragma unroll
  for (int j=0;j<2;j++){
    int slot = t + (j<<8);
    sOff[j] = (size_t)(slot>>2)*K + ((slot&3)<<3);
  }
  auto stage = [&](int k0, int buf){
    char* ad = (char*)As + (buf<<13) + (w<<10);
    char* bd = (char*)Bs + (buf<<13) + (w<<10);
    #pragma unroll
    for (int j=0;j<2;j++){
      GLOAD16(Ab + sOff[j] + k0, ad + (j<<12));
      GLOAD16(Bb + sOff[j] + k0, bd + (j<<12));
    }
  };
  f32x4 acc[4][4] = {};
  const int mw = (w&1)<<6, nw = (w>>1)<<6;
  const int nk = K>>5;
  int buf = 0;
  stage(0, 0);
  asm volatile("s_waitcnt vmcnt(0)" ::: "memory");
  __syncthreads();
  for (int ks=0; ks<nk; ++ks){
    if (ks+1 < nk) stage((ks+1)<<5, buf^1);
    bf16x8 af[4], bfm[4];
    #pragma unroll
    for (int mf=0;mf<4;mf++)
      af[mf] = *reinterpret_cast<const bf16x8*>(&As[buf][(mw + mf*16 + (l&15))*32 + (g<<3)]);
    #pragma unroll
    for (int nf=0;nf<4;nf++)
      bfm[nf] = *reinterpret_cast<const bf16x8*>(&Bs[buf][(nw + nf*16 + (l&15))*32 + (g<<3)]);
    #pragma unroll
    for (int mf=0;mf<4;mf++)
      #pragma unroll
      for (int nf=0;nf<4;nf++)
        acc[mf][nf] = __builtin_amdgcn_mfma_f32_16x16x32_bf16(af[mf], bfm[nf], acc[mf][nf], 0,0,0);
    asm volatile("s_waitcnt vmcnt(0)" ::: "memory");
    __syncthreads();
    buf ^= 1;
  }
  if constexpr (EPI==0){
    #pragma unroll
    for (int nf=0;nf<4;nf++){
      const int col = n0 + nw + nf*16 + (l&15);
      const int sec = col>>11; const int rem = col&2047;
      const int hh = rem>>7;  const int dd = rem&127;
      bf16* dst = (sec==0) ? q_out : ((sec==1) ? k_out : v_out);
      const float bv = bias[col];
      #pragma unroll
      for (int mf=0;mf<4;mf++)
        #pragma unroll
        for (int ri=0;ri<4;ri++){
          const int row = m0 + mw + mf*16 + (g<<2) + ri;
          const int bb = row>>10, qp = row&1023;
          dst[(((size_t)(bb*16+hh)*1024 + qp)<<7) + dd] = (bf16)(acc[mf][nf][ri] + bv);
        }
    }
  } else {
    #pragma unroll
    for (int nf=0;nf<4;nf++){
      const int col = n0 + nw + nf*16 + (l&15);
      const float bv = bias[col];
      #pragma unroll
      for (int mf=0;mf<4;mf++)
        #pragma unroll
        for (int ri=0;ri<4;ri++){
          const int row = m0 + mw + mf*16 + (g<<2) + ri;
          c_out[(size_t)row*N + col] = acc[mf][nf][ri] + bv;
        }
    }
  }
}

// ---------------- fused paged + causal flash attention ----------------
// block = (b, h, 128-row q-tile); 4 waves x 32 q-rows (mq=2 x 16).
// Swapped QK^T: S^T = mfma(K, Q) -> lane holds q = l&15, kv = cb*16 + 4g + ri.
// V rows pi-permuted in LDS so PV A-frag = pure register repack (no shuffles, no P-LDS).
__global__ __launch_bounds__(256,2) void k_attn(
    const bf16* __restrict__ qb, const bf16* __restrict__ kb, const bf16* __restrict__ vb,
    const bf16* __restrict__ kpb, const bf16* __restrict__ vpb,
    const int* __restrict__ page_pos, const int* __restrict__ input_pos,
    bf16* __restrict__ ctx)
{
  __shared__ bf16 Ks[2*64*128];   // [buf][kv][d] row-major, XOR-swizzled (swz on read, inv-swz source)
  __shared__ bf16 Vs[2*64*128];   // [buf] subtiled for ds_read_b64_tr_b16, rows pi-permuted
  const int t = threadIdx.x, w = t>>6, l = t&63, g = l>>4, c = l&15;
  const int bid = blockIdx.x;
  const int wg = (bid&7)*128 + (bid>>3);
  const int qt = wg & 7, h = (wg>>3)&15, b = wg>>7;
  const int q0w = (qt<<7) + (w<<5);
  const float scale = 0.088388347648318447f; // 1/sqrt(128)
  const size_t bh = (size_t)(b*16 + h);

  const bf16* qptr = qb + (bh<<17);
  bf16x8 qf[2][4];
  #pragma unroll
  for (int mq=0;mq<2;mq++)
    #pragma unroll
    for (int kc=0;kc<4;kc++)
      qf[mq][kc] = *reinterpret_cast<const bf16x8*>(qptr + ((size_t)(q0w + mq*16 + c)<<7) + kc*32 + (g<<3));

  int kOff[4], vOff[4];
  #pragma unroll
  for (int j=0;j<4;j++){
    const int slot = t + (j<<8);
    { // K: linear LDS dest; source inverse-swizzled so swizzled reads see row-major
      const int a = slot<<4; const int r = a>>8; const int co = (a&255) ^ ((r&7)<<4);
      kOff[j] = (r<<7) + (co>>1);
    }
    { // V: subtiled dest slot s covers u={2s,2s+1}: p = same, d0..d0+7 contiguous
      const int s_ = slot;
      const int p  = ((s_>>6)<<2) | ((s_>>1)&3);
      const int d0 = (((s_>>3)&7)<<4) | ((s_&1)<<3);
      const int pp = (p&32) | ((p&4)<<2) | (((p>>3)&3)<<2) | (p&3); // pi(p)
      vOff[j] = (pp<<7) + d0;
    }
  }
  const bf16* kcb = kb + (bh<<17);
  const bf16* vcb = vb + (bh<<17);
  const int len_b = input_pos[b*2+1];
  const int NT = 32 + ((qt+1)<<1);

  f32x4 o[2][8] = {};
  float mrow[2] = {-3e38f,-3e38f};
  float lsum[2] = {0.f,0.f};

  auto tsrc = [&](int T, const bf16*& ks, const bf16*& vs_){
    if (T < 32){
      size_t pb = ((((size_t)(T>>2)<<3) + (size_t)b)*16 + (size_t)h) << 15;
      size_t off = (size_t)(T&3)<<13;
      ks = kpb + pb + off; vs_ = vpb + pb + off;
    } else {
      int kt = T-32; ks = kcb + ((size_t)kt<<13); vs_ = vcb + ((size_t)kt<<13);
    }
  };
  auto stage = [&](int T, int buf){
    const bf16 *ks, *vs_; tsrc(T, ks, vs_);
    char* kd = (char*)Ks + (buf<<14) + (w<<10);
    char* vd = (char*)Vs + (buf<<14) + (w<<10);
    #pragma unroll
    for (int j=0;j<4;j++){
      GLOAD16(ks  + kOff[j], kd + (j<<12));
      GLOAD16(vs_ + vOff[j], vd + (j<<12));
    }
  };

  auto process = [&](int buf, int lo, int hi, bool causal, int ktg){
    const char* Kb = (const char*)Ks + (buf<<14);
    const char* Vb = (const char*)Vs + (buf<<14);
    // QK^T (swapped): s[cb][mq], lane: q = q0w+mq*16+c, kv = cb*16 + 4g + ri
    f32x4 s[4][2] = {{},{},{},{}};
    #pragma unroll
    for (int kc=0;kc<4;kc++){
      bf16x8 kf[4];
      #pragma unroll
      for (int cb=0;cb<4;cb++){
        const int krow = (cb<<4) + c;
        unsigned a = (unsigned)((krow<<8) + (kc<<6) + (g<<4)); a ^= (unsigned)((krow&7)<<4);
        kf[cb] = *reinterpret_cast<const bf16x8*>(Kb + a);
      }
      __builtin_amdgcn_s_setprio(1);
      #pragma unroll
      for (int cb=0;cb<4;cb++)
        #pragma unroll
        for (int mq=0;mq<2;mq++)
          s[cb][mq] = __builtin_amdgcn_mfma_f32_16x16x32_bf16(kf[cb], qf[mq][kc], s[cb][mq], 0,0,0);
      __builtin_amdgcn_s_setprio(0);
    }
    // mask + scale
    #pragma unroll
    for (int cb=0;cb<4;cb++)
      #pragma unroll
      for (int ri=0;ri<4;ri++){
        const int kvl = (cb<<4) + (g<<2) + ri;
        const bool vok = (kvl >= lo) && (kvl < hi);
        #pragma unroll
        for (int mq=0;mq<2;mq++){
          bool ok = vok;
          if (causal) ok = ok && ((ktg + kvl) <= (q0w + mq*16 + c));
          s[cb][mq][ri] = ok ? s[cb][mq][ri]*scale : -3e38f;
        }
      }
    // online softmax with defer-max (T13, THR=8)
    #pragma unroll
    for (int mq=0;mq<2;mq++){
      float mx = -3e38f;
      #pragma unroll
      for (int cb=0;cb<4;cb++)
        #pragma unroll
        for (int ri=0;ri<4;ri++) mx = fmaxf(mx, s[cb][mq][ri]);
      mx = fmaxf(mx, __shfl_xor(mx, 16, 64));
      mx = fmaxf(mx, __shfl_xor(mx, 32, 64));
      const int defer = __all(mx - mrow[mq] <= 8.f);
      if (!defer){
        const float mn = fmaxf(mrow[mq], mx);
        const float al = __expf(mrow[mq] - mn);
        mrow[mq] = mn;
        lsum[mq] *= al;
        #pragma unroll
        for (int ri=0;ri<4;ri++){
          const float av = __shfl(al, (l&48) | ((g<<2)+ri), 64);
          #pragma unroll
          for (int dcb=0;dcb<8;dcb++) o[mq][dcb][ri] *= av;
        }
      }
      float ps = 0.f;
      #pragma unroll
      for (int cb=0;cb<4;cb++)
        #pragma unroll
        for (int ri=0;ri<4;ri++){
          const float e = __expf(s[cb][mq][ri] - mrow[mq]);
          s[cb][mq][ri] = e; ps += e;
        }
      lsum[mq] += ps;
    }
    // PV: per-kc batched tr_reads (issue 16, wait once), A-frag from registers
    #pragma unroll
    for (int kc=0;kc<2;kc++){
      u16x4 vr0[8], vr1[8];
      #pragma unroll
      for (int dcb=0;dcb<8;dcb++){
        const unsigned sub = ((unsigned)((((kc<<3) + (g<<1))<<3) + dcb)<<7) + ((unsigned)c<<3);
        as3_void* pl = (as3_void*)(Vb + sub);
        asm volatile("ds_read_b64_tr_b16 %0, %2 offset:0\n\t"
                     "ds_read_b64_tr_b16 %1, %2 offset:1024"
                     : "=&v"(vr0[dcb]), "=&v"(vr1[dcb]) : "v"(pl) : "memory");
      }
      // build P A-frags while the LDS reads are in flight
      bf16x8 pav[2];
      #pragma unroll
      for (int mq=0;mq<2;mq++)
        #pragma unroll
        for (int e=0;e<8;e++)
          pav[mq][e] = (bf16)s[(kc<<1)+(e>>2)][mq][e&3];
      asm volatile("s_waitcnt lgkmcnt(0)" ::: "memory");
      __builtin_amdgcn_sched_barrier(0);
      __builtin_amdgcn_s_setprio(1);
      #pragma unroll
      for (int dcb=0;dcb<8;dcb++){
        union { unsigned short us[8]; bf16x8 v; } uu;
        #pragma unroll
        for (int i=0;i<4;i++){ uu.us[i]=vr0[dcb][i]; uu.us[4+i]=vr1[dcb][i]; }
        #pragma unroll
        for (int mq=0;mq<2;mq++)
          o[mq][dcb] = __builtin_amdgcn_mfma_f32_16x16x32_bf16(pav[mq], uu.v, o[mq][dcb], 0,0,0);
      }
      __builtin_amdgcn_s_setprio(0);
    }
  };

  // ---- pipelined tile loop: stage(T+1) || process(T) ----
  int buf = 0;
  stage(0, 0);
  asm volatile("s_waitcnt vmcnt(0)" ::: "memory");
  __syncthreads();
  for (int T=0; T<NT; ++T){
    if (T+1 < NT) stage(T+1, buf^1);
    int lo, hi, ktg; bool causal;
    if (T < 32){
      const int pg = T>>2, to = T&3;
      const int start = page_pos[(pg*8+b)*2], plen = page_pos[(pg*8+b)*2+1];
      lo = start - (to<<6); hi = start + plen - (to<<6); causal = false; ktg = 0;
    } else {
      const int kt = T-32; lo = 0; hi = len_b - (kt<<6); if (hi>64) hi=64; causal = true; ktg = kt<<6;
    }
    process(buf, lo, hi, causal, ktg);
    asm volatile("s_waitcnt vmcnt(0)" ::: "memory");
    __syncthreads();
    buf ^= 1;
  }

  // ---- epilogue: ctx[b][q][h*128+d] (bf16); q = q0w + mq*16 + 4g + ri, d = dcb*16 + c ----
  #pragma unroll
  for (int mq=0;mq<2;mq++){
    float tl = lsum[mq];
    tl += __shfl_xor(tl, 16, 64);
    tl += __shfl_xor(tl, 32, 64);
    const float inv = 1.f / fmaxf(tl, 1e-9f);
    #pragma unroll
    for (int ri=0;ri<4;ri++){
      const float iv = __shfl(inv, (l&48) | ((g<<2)+ri), 64);
      const int q = q0w + mq*16 + (g<<2) + ri;
      #pragma unroll
      for (int dcb=0;dcb<8;dcb++)
        ctx[(((size_t)(b<<10) + q)<<11) + (h<<7) + (dcb<<4) + c] = (bf16)(o[mq][dcb][ri]*iv);
    }
  }
}

// ---------------- launcher ----------------
extern "C" void kernel_launch(void* const* d_in, const int* in_sizes, int n_in,
                              void* d_out, int out_size, void* d_ws, size_t ws_size,
                              hipStream_t stream)
{
  const float* hidden  = (const float*)d_in[0];
  const float* W_attn  = (const float*)d_in[1];
  const float* b_attn  = (const float*)d_in[2];
  const float* W_proj  = (const float*)d_in[3];
  const float* b_proj  = (const float*)d_in[4];
  const float* k_pages = (const float*)d_in[5];
  const float* v_pages = (const float*)d_in[6];
  const int*   page_pos  = (const int*)d_in[7];
  const int*   input_pos = (const int*)d_in[8];
  float* out = (float*)d_out;
  char* ws = (char*)d_ws;
  bf16* A1  = (bf16*)(ws);              // 8192x2048 bf16 (32MB); reused as ctx
  bf16* Wt1 = (bf16*)(ws + 33554432);   // 6144x2048 bf16 (24MB)
  bf16* Wt2 = (bf16*)(ws + 58720256);   // 2048x2048 bf16 (8MB)
  bf16* qb  = (bf16*)(ws + 67108864);   // [8,16,1024,128] bf16 (32MB)
  bf16* kb  = (bf16*)(ws + 100663296);
  bf16* vb  = (bf16*)(ws + 134217728);
  bf16* kpb = (bf16*)(ws + 167772160);  // bf16 pages (64MB)
  bf16* vpb = (bf16*)(ws + 234881024);  // bf16 pages (64MB); end 301,989,888
  bf16* ctx = A1;

  k_cvt_bf16<<<16384, 256, 0, stream>>>(hidden, A1, 4194304);
  k_cvt_bf16<<<32768, 256, 0, stream>>>(k_pages, kpb, 8388608);
  k_cvt_bf16<<<32768, 256, 0, stream>>>(v_pages, vpb, 8388608);
  k_transpose_cvt<<<dim3(192,64), 256, 0, stream>>>(W_attn, Wt1, 2048, 6144);
  k_transpose_cvt<<<dim3(64,64),  256, 0, stream>>>(W_proj, Wt2, 2048, 2048);
  k_gemm<0><<<64*48, 256, 0, stream>>>(A1, Wt1, b_attn, 6144, 2048, qb, kb, vb, nullptr);
  k_attn<<<1024, 256, 0, stream>>>(qb, kb, vb, kpb, vpb, page_pos, input_pos, ctx);
  k_gemm<1><<<64*16, 256, 0, stream>>>(ctx, Wt2, b_proj, 2048, 2048, nullptr, nullptr, nullptr, out);
}